// Round 1
// baseline (1877.957 us; speedup 1.0000x reference)
//
#include <hip/hip_runtime.h>
#include <math.h>

#define NN 16384
#define KK 16
#define TJ 512
#define TJP (TJ + 4)            // padded LDS row stride (floats); keeps b128 16B-aligned
#define ROWS_PER_BLOCK 16
#define ROWS_PER_WAVE 4
#define THREADS 256

// ws float layout:
// [0]      total_s  = sum_{i,j} adj[i,j] * dot(C_i, C_j)
// [1]      m_sum    = sum(deg)
// [2..17]  dC[k]    = sum_i deg_i * C[i,k]
// [18..33] colsum[k]= sum_i C[i,k]
// [64..64+NN) deg[i]

__global__ void zero_acc(float* ws) {
    int t = threadIdx.x;
    if (t < 64) ws[t] = 0.0f;
}

__global__ void __launch_bounds__(THREADS, 4)
k1_stream(const float* __restrict__ adj, const float* __restrict__ C,
          float* __restrict__ ws) {
    __shared__ float ct[KK * TJP];   // transposed C tile: ct[k*TJP + j]

    const int tid  = threadIdx.x;
    const int lane = tid & 63;
    const int wave = __builtin_amdgcn_readfirstlane(tid >> 6);
    const int i0   = blockIdx.x * ROWS_PER_BLOCK + wave * ROWS_PER_WAVE;

    // C_i for this wave's 4 rows -> force into SGPRs (wave-uniform)
    float ci[ROWS_PER_WAVE][KK];
    #pragma unroll
    for (int r = 0; r < ROWS_PER_WAVE; ++r) {
        #pragma unroll
        for (int k = 0; k < KK; ++k) {
            float v = C[(size_t)(i0 + r) * KK + k];
            ci[r][k] = __uint_as_float(
                __builtin_amdgcn_readfirstlane(__float_as_uint(v)));
        }
    }

    float s[ROWS_PER_WAVE]  = {0.f, 0.f, 0.f, 0.f};
    float dg[ROWS_PER_WAVE] = {0.f, 0.f, 0.f, 0.f};

    for (int jt = 0; jt < NN; jt += TJ) {
        __syncthreads();   // protect previous tile's reads before overwriting
        // Stage C[jt .. jt+TJ) transposed into LDS. 8192 floats, 8 f4/thread.
        #pragma unroll
        for (int it = 0; it < (TJ * KK) / (THREADS * 4); ++it) {
            int idx = tid * 4 + it * THREADS * 4;       // float idx in tile
            float4 v = *(const float4*)(C + (size_t)jt * KK + idx);
            int j  = idx >> 4;      // idx / 16
            int k0 = idx & 15;      // multiple of 4
            ct[(k0 + 0) * TJP + j] = v.x;
            ct[(k0 + 1) * TJP + j] = v.y;
            ct[(k0 + 2) * TJP + j] = v.z;
            ct[(k0 + 3) * TJP + j] = v.w;
        }
        __syncthreads();

        #pragma unroll
        for (int jb = 0; jb < TJ; jb += 256) {
            const int jo = jb + lane * 4;          // offset within tile
            const int j  = jt + jo;                // global column

            float4 a[ROWS_PER_WAVE];
            #pragma unroll
            for (int r = 0; r < ROWS_PER_WAVE; ++r)
                a[r] = *(const float4*)(adj + (size_t)(i0 + r) * NN + j);

            float d[ROWS_PER_WAVE][4] = {};
            #pragma unroll
            for (int k = 0; k < KK; ++k) {
                float4 c4 = *(const float4*)(&ct[k * TJP + jo]);
                #pragma unroll
                for (int r = 0; r < ROWS_PER_WAVE; ++r) {
                    d[r][0] += ci[r][k] * c4.x;
                    d[r][1] += ci[r][k] * c4.y;
                    d[r][2] += ci[r][k] * c4.z;
                    d[r][3] += ci[r][k] * c4.w;
                }
            }
            #pragma unroll
            for (int r = 0; r < ROWS_PER_WAVE; ++r) {
                s[r]  += a[r].x * d[r][0] + a[r].y * d[r][1]
                       + a[r].z * d[r][2] + a[r].w * d[r][3];
                dg[r] += a[r].x + a[r].y + a[r].z + a[r].w;
            }
        }
    }

    // Wave-reduce s and deg across 64 lanes
    float tot = 0.f;
    #pragma unroll
    for (int r = 0; r < ROWS_PER_WAVE; ++r) {
        #pragma unroll
        for (int off = 32; off; off >>= 1) {
            s[r]  += __shfl_xor(s[r],  off, 64);
            dg[r] += __shfl_xor(dg[r], off, 64);
        }
        tot += s[r];
    }
    if (lane == 0) {
        #pragma unroll
        for (int r = 0; r < ROWS_PER_WAVE; ++r)
            ws[64 + i0 + r] = dg[r];
        atomicAdd(&ws[0], tot);
    }
}

// 64 blocks x 256 threads: exactly one row per thread.
__global__ void k2_rows(const float* __restrict__ C, float* __restrict__ ws) {
    const int i    = blockIdx.x * blockDim.x + threadIdx.x;   // 0..16383
    const int lane = threadIdx.x & 63;
    const float deg = ws[64 + i];

    float c[KK];
    #pragma unroll
    for (int q = 0; q < 4; ++q) {
        float4 v = *(const float4*)(C + (size_t)i * KK + q * 4);
        c[q*4+0] = v.x; c[q*4+1] = v.y; c[q*4+2] = v.z; c[q*4+3] = v.w;
    }

    float vals[33];
    #pragma unroll
    for (int k = 0; k < KK; ++k) { vals[k] = deg * c[k]; vals[16 + k] = c[k]; }
    vals[32] = deg;

    #pragma unroll
    for (int v = 0; v < 33; ++v) {
        #pragma unroll
        for (int off = 32; off; off >>= 1)
            vals[v] += __shfl_xor(vals[v], off, 64);
    }
    if (lane == 0) {
        #pragma unroll
        for (int k = 0; k < KK; ++k) {
            atomicAdd(&ws[2 + k],  vals[k]);
            atomicAdd(&ws[18 + k], vals[16 + k]);
        }
        atomicAdd(&ws[1], vals[32]);
    }
}

__global__ void k3_final(const float* __restrict__ ws,
                         const float* __restrict__ beta,
                         float* __restrict__ out) {
    if (threadIdx.x == 0 && blockIdx.x == 0) {
        double total_s = (double)ws[0];
        double m       = (double)ws[1] * 0.5;
        double dd = 0.0;
        for (int k = 0; k < KK; ++k)
            dd += (double)ws[2 + k] * (double)ws[2 + k];
        double mod_term = total_s - dd / (2.0 * m);
        double mod_loss = -mod_term / (2.0 * m);
        double col = 0.0;
        for (int k = 0; k < KK; ++k)
            col += fabs((double)ws[18 + k] - 1.0);
        double res = mod_loss + (double)beta[0] * (4.0 / 16384.0) * col;
        out[0] = (float)res;
    }
}

extern "C" void kernel_launch(void* const* d_in, const int* in_sizes, int n_in,
                              void* d_out, int out_size, void* d_ws, size_t ws_size,
                              hipStream_t stream) {
    const float* C    = (const float*)d_in[0];
    // d_in[1] = X, unused by the reference loss
    const float* adj  = (const float*)d_in[2];
    const float* beta = (const float*)d_in[3];
    float* ws  = (float*)d_ws;
    float* out = (float*)d_out;

    zero_acc<<<1, 64, 0, stream>>>(ws);
    k1_stream<<<NN / ROWS_PER_BLOCK, THREADS, 0, stream>>>(adj, C, ws);
    k2_rows<<<NN / 256, 256, 0, stream>>>(C, ws);
    k3_final<<<1, 64, 0, stream>>>(ws, beta, out);
}